// Round 1
// baseline (310.160 us; speedup 1.0000x reference)
//
#include <hip/hip_runtime.h>

#define DD 128
#define KK 384
#define NG 512

typedef __attribute__((ext_vector_type(8))) short bf16x8;
typedef __attribute__((ext_vector_type(4))) float f32x4;

__device__ __forceinline__ float bf2f(unsigned short u) {
  return __uint_as_float(((unsigned int)u) << 16);
}
__device__ __forceinline__ unsigned short f2bf(float f) {
  unsigned int x = __float_as_uint(f);
  x += 0x7fffu + ((x >> 16) & 1u);
  return (unsigned short)(x >> 16);
}

__global__ void k_zero2(int* __restrict__ a, int* __restrict__ b, int n) {
  int i = blockIdx.x * blockDim.x + threadIdx.x;
  if (i < n) { a[i] = 0; b[i] = 0; }
}

__global__ void k_count(const int* __restrict__ dst, int* __restrict__ counts, int E) {
  int e = blockIdx.x * blockDim.x + threadIdx.x;
  if (e < E) atomicAdd(counts + dst[e], 1);
}

__global__ __launch_bounds__(1024) void k_scan(const int* __restrict__ counts,
                                               int* __restrict__ row_start, int n) {
  __shared__ int wsum[16];
  __shared__ int carry_s;
  int tid = threadIdx.x;
  int lane = tid & 63, wid = tid >> 6;
  if (tid == 0) { carry_s = 0; row_start[0] = 0; }
  __syncthreads();
  for (int base = 0; base < n; base += 1024) {
    int idx = base + tid;
    int v = (idx < n) ? counts[idx] : 0;
    int s = v;
#pragma unroll
    for (int off = 1; off < 64; off <<= 1) {
      int t = __shfl_up(s, off);
      if (lane >= off) s += t;
    }
    if (lane == 63) wsum[wid] = s;
    __syncthreads();
    if (wid == 0 && lane < 16) {
      int ws = wsum[lane];
#pragma unroll
      for (int off = 1; off < 16; off <<= 1) {
        int t = __shfl_up(ws, off);
        if (lane >= off) ws += t;
      }
      wsum[lane] = ws;
    }
    __syncthreads();
    int prev = (wid > 0) ? wsum[wid - 1] : 0;
    int incl = s + prev + carry_s;
    if (idx < n) row_start[idx + 1] = incl;
    int total = wsum[15];
    __syncthreads();
    if (tid == 0) carry_s += total;
    __syncthreads();
  }
}

__global__ void k_scatter(const int* __restrict__ srcv, const int* __restrict__ dstv,
                          const int* __restrict__ row_start, int* __restrict__ cursor,
                          int* __restrict__ csr, int E) {
  int e = blockIdx.x * blockDim.x + threadIdx.x;
  if (e < E) {
    int d = dstv[e];
    int pos = row_start[d] + atomicAdd(cursor + d, 1);
    csr[pos] = srcv[e];
  }
}

__global__ void k_convert(const float* __restrict__ h, const float* __restrict__ x,
                          unsigned short* __restrict__ hbf, unsigned short* __restrict__ xbf,
                          int n128, int mpad128) {
  int i = (blockIdx.x * blockDim.x + threadIdx.x) * 4;
  if (i >= mpad128) return;
  ushort4 ho, xo;
  if (i < n128) {
    float4 hv = *(const float4*)(h + i);
    float4 xv = *(const float4*)(x + i);
    ho = make_ushort4(f2bf(hv.x), f2bf(hv.y), f2bf(hv.z), f2bf(hv.w));
    xo = make_ushort4(f2bf(xv.x), f2bf(xv.y), f2bf(xv.z), f2bf(xv.w));
  } else {
    ho = make_ushort4(0, 0, 0, 0);
    xo = make_ushort4(0, 0, 0, 0);
  }
  *(ushort4*)(hbf + i) = ho;
  *(ushort4*)(xbf + i) = xo;
}

__global__ void k_agg(const float* __restrict__ h, const int* __restrict__ row_start,
                      const int* __restrict__ csr, unsigned short* __restrict__ aggbf,
                      int n, int mpad) {
  int wave = (blockIdx.x * blockDim.x + threadIdx.x) >> 6;
  int lane = threadIdx.x & 63;
  if (wave >= mpad) return;
  float a0 = 0.f, a1 = 0.f;
  if (wave < n) {
    int s = row_start[wave], e = row_start[wave + 1];
    for (int j = s; j < e; ++j) {
      int src = csr[j];
      const float* hr = h + (size_t)src * DD;
      a0 += hr[lane];
      a1 += hr[lane + 64];
    }
    float inv = 1.f / fmaxf((float)(e - s), 1.f);
    a0 *= inv;
    a1 *= inv;
  }
  aggbf[(size_t)wave * DD + lane] = f2bf(a0);
  aggbf[(size_t)wave * DD + 64 + lane] = f2bf(a1);
}

__global__ void k_fusew(const float* __restrict__ Wg0, const float* __restrict__ Wg1,
                        const float* __restrict__ Wg2, const float* __restrict__ Wg3,
                        const float* __restrict__ Wl0, const float* __restrict__ Wl1,
                        const float* __restrict__ Wl2, const float* __restrict__ Wl3,
                        const float* __restrict__ Wr0, const float* __restrict__ Wr1,
                        const float* __restrict__ Wr2, const float* __restrict__ Wr3,
                        const float* __restrict__ bg0, const float* __restrict__ bg1,
                        const float* __restrict__ bg2, const float* __restrict__ bg3,
                        const float* __restrict__ bl0, const float* __restrict__ bl1,
                        const float* __restrict__ bl2, const float* __restrict__ bl3,
                        unsigned short* __restrict__ Ut, float* __restrict__ bias) {
  int id = blockIdx.x * blockDim.x + threadIdx.x;
  if (id >= NG * KK) return;
  int nn = id / KK, k = id % KK;
  int g = nn >> 7, c = nn & 127;
  const float* Wg = g == 0 ? Wg0 : g == 1 ? Wg1 : g == 2 ? Wg2 : Wg3;
  const float* Wl = g == 0 ? Wl0 : g == 1 ? Wl1 : g == 2 ? Wl2 : Wl3;
  const float* Wr = g == 0 ? Wr0 : g == 1 ? Wr1 : g == 2 ? Wr2 : Wr3;
  float v;
  if (k < 128)      v = Wg[k * DD + c] + Wr[k * DD + c];
  else if (k < 256) v = Wg[k * DD + c];
  else              v = Wl[(k - 256) * DD + c];
  Ut[(size_t)nn * KK + k] = f2bf(v);
  if (k == 0) {
    const float* bgp = g == 0 ? bg0 : g == 1 ? bg1 : g == 2 ? bg2 : bg3;
    const float* blp = g == 0 ? bl0 : g == 1 ? bl1 : g == 2 ? bl2 : bl3;
    bias[nn] = bgp[c] + blp[c];
  }
}

__device__ __forceinline__ void gload16(const void* g, void* l) {
  __builtin_amdgcn_global_load_lds((__attribute__((address_space(1))) void*)(void*)g,
                                   (__attribute__((address_space(3))) void*)l, 16, 0, 0);
}

__global__ __launch_bounds__(256) void k_gemm(
    const unsigned short* __restrict__ hbf, const unsigned short* __restrict__ xbf,
    const unsigned short* __restrict__ aggbf, const unsigned short* __restrict__ Ut,
    const float* __restrict__ bias, unsigned short* __restrict__ G, int nrows) {
  __shared__ unsigned short As[128 * 64];
  __shared__ unsigned short Bs[128 * 64];
  int m0 = blockIdx.x * 128;
  int n0 = blockIdx.y * 128;
  int tid = threadIdx.x;
  int w = tid >> 6, lane = tid & 63;
  int wr = w >> 1, wc = w & 1;
  f32x4 acc[4][4] = {};

  int srow[4], sslot[4];
#pragma unroll
  for (int p = 0; p < 4; ++p) {
    int off = w * 4096 + p * 1024 + lane * 16;
    srow[p] = off >> 7;
    sslot[p] = (lane & 7) ^ (srow[p] & 7);
  }

  for (int ks = 0; ks < 6; ++ks) {
    const unsigned short* Ab = ks < 2 ? hbf : (ks < 4 ? xbf : aggbf);
    int akoff = (ks & 1) * 128;  // byte offset within 256B source row
    int bkoff = ks * 128;        // byte offset within 768B Ut row
#pragma unroll
    for (int p = 0; p < 4; ++p) {
      const char* ga = (const char*)Ab + (size_t)(m0 + srow[p]) * 256 + akoff + sslot[p] * 16;
      gload16(ga, (char*)As + w * 4096 + p * 1024);
      const char* gb = (const char*)Ut + (size_t)(n0 + srow[p]) * 768 + bkoff + sslot[p] * 16;
      gload16(gb, (char*)Bs + w * 4096 + p * 1024);
    }
    asm volatile("s_waitcnt vmcnt(0)" ::: "memory");
    __syncthreads();

    bf16x8 af[4][2], bfr[4][2];
    int rg = lane >> 4;
#pragma unroll
    for (int mi = 0; mi < 4; ++mi) {
      int r = wr * 64 + mi * 16 + (lane & 15);
#pragma unroll
      for (int k2 = 0; k2 < 2; ++k2) {
        int s = (k2 * 4 + rg) ^ (r & 7);
        af[mi][k2] = *(const bf16x8*)((const char*)As + r * 128 + s * 16);
      }
    }
#pragma unroll
    for (int ni = 0; ni < 4; ++ni) {
      int r = wc * 64 + ni * 16 + (lane & 15);
#pragma unroll
      for (int k2 = 0; k2 < 2; ++k2) {
        int s = (k2 * 4 + rg) ^ (r & 7);
        bfr[ni][k2] = *(const bf16x8*)((const char*)Bs + r * 128 + s * 16);
      }
    }
#pragma unroll
    for (int mi = 0; mi < 4; ++mi)
#pragma unroll
      for (int ni = 0; ni < 4; ++ni) {
        acc[mi][ni] = __builtin_amdgcn_mfma_f32_16x16x32_bf16(af[mi][0], bfr[ni][0], acc[mi][ni], 0, 0, 0);
        acc[mi][ni] = __builtin_amdgcn_mfma_f32_16x16x32_bf16(af[mi][1], bfr[ni][1], acc[mi][ni], 0, 0, 0);
      }
    __syncthreads();
  }

  int colb = n0 + wc * 64;
#pragma unroll
  for (int ni = 0; ni < 4; ++ni) {
    int col = colb + ni * 16 + (lane & 15);
    float bi = bias[col];
#pragma unroll
    for (int mi = 0; mi < 4; ++mi) {
      int rowb = m0 + wr * 64 + mi * 16 + (lane >> 4) * 4;
#pragma unroll
      for (int j = 0; j < 4; ++j) {
        int row = rowb + j;
        if (row < nrows) G[(size_t)row * NG + col] = f2bf(acc[mi][ni][j] + bi);
      }
    }
  }
}

__global__ void k_final(const unsigned short* __restrict__ G, const float* __restrict__ cell,
                        const float* __restrict__ gamma, const float* __restrict__ beta,
                        float* __restrict__ out, int n) {
  int wave = (blockIdx.x * blockDim.x + threadIdx.x) >> 6;
  int lane = threadIdx.x & 63;
  if (wave >= n) return;
  const unsigned short* g = G + (size_t)wave * NG;
  int c = lane * 2;
  ushort2 fu = *(const ushort2*)(g + c);
  ushort2 iu = *(const ushort2*)(g + 128 + c);
  ushort2 cu = *(const ushort2*)(g + 256 + c);
  ushort2 ou = *(const ushort2*)(g + 384 + c);
  float2 cv = *(const float2*)(cell + (size_t)wave * DD + c);
  float f0 = 1.f / (1.f + expf(-bf2f(fu.x)));
  float f1 = 1.f / (1.f + expf(-bf2f(fu.y)));
  float i0 = 1.f / (1.f + expf(-bf2f(iu.x)));
  float i1 = 1.f / (1.f + expf(-bf2f(iu.y)));
  float t0 = tanhf(bf2f(cu.x));
  float t1 = tanhf(bf2f(cu.y));
  float o0 = 1.f / (1.f + expf(-bf2f(ou.x)));
  float o1 = 1.f / (1.f + expf(-bf2f(ou.y)));
  float cn0 = f0 * cv.x + i0 * t0;
  float cn1 = f1 * cv.y + i1 * t1;
  float y0 = o0 * tanhf(cn0);
  float y1 = o1 * tanhf(cn1);
  float s = y0 + y1, s2 = y0 * y0 + y1 * y1;
#pragma unroll
  for (int off = 1; off < 64; off <<= 1) {
    s += __shfl_xor(s, off);
    s2 += __shfl_xor(s2, off);
  }
  float mean = s * (1.f / 128.f);
  float var = s2 * (1.f / 128.f) - mean * mean;
  float rstd = rsqrtf(var + 1e-5f);
  float2 gm = *(const float2*)(gamma + c);
  float2 bt = *(const float2*)(beta + c);
  float h0 = (y0 - mean) * rstd * gm.x + bt.x;
  float h1 = (y1 - mean) * rstd * gm.y + bt.y;
  *(float2*)(out + (size_t)wave * DD + c) = make_float2(h0, h1);
  *(float2*)(out + (size_t)n * DD + (size_t)wave * DD + c) = make_float2(cn0, cn1);
}

extern "C" void kernel_launch(void* const* d_in, const int* in_sizes, int n_in,
                              void* d_out, int out_size, void* d_ws, size_t ws_size,
                              hipStream_t stream) {
  const float* h = (const float*)d_in[0];
  const float* cellp = (const float*)d_in[1];
  const float* x = (const float*)d_in[2];
  const int* edge = (const int*)d_in[3];
  const float* Wg0 = (const float*)d_in[4];
  const float* bg0 = (const float*)d_in[5];
  const float* Wg1 = (const float*)d_in[6];
  const float* bg1 = (const float*)d_in[7];
  const float* Wg2 = (const float*)d_in[8];
  const float* bg2 = (const float*)d_in[9];
  const float* Wg3 = (const float*)d_in[10];
  const float* bg3 = (const float*)d_in[11];
  const float* Wl0 = (const float*)d_in[12];
  const float* bl0 = (const float*)d_in[13];
  const float* Wr0 = (const float*)d_in[14];
  const float* Wl1 = (const float*)d_in[15];
  const float* bl1 = (const float*)d_in[16];
  const float* Wr1 = (const float*)d_in[17];
  const float* Wl2 = (const float*)d_in[18];
  const float* bl2 = (const float*)d_in[19];
  const float* Wr2 = (const float*)d_in[20];
  const float* Wl3 = (const float*)d_in[21];
  const float* bl3 = (const float*)d_in[22];
  const float* Wr3 = (const float*)d_in[23];
  const float* gamma = (const float*)d_in[24];
  const float* beta = (const float*)d_in[25];

  int N = in_sizes[0] / DD;
  int E = in_sizes[3] / 2;
  int Mpad = ((N + 127) / 128) * 128;

  char* ws = (char*)d_ws;
  size_t off = 0;
  auto alloc = [&](size_t b) {
    char* p = ws + off;
    off += (b + 255) & ~(size_t)255;
    return p;
  };
  int* counts = (int*)alloc((size_t)N * 4);
  int* cursor = (int*)alloc((size_t)N * 4);
  int* row_start = (int*)alloc((size_t)(N + 1) * 4);
  int* csr = (int*)alloc((size_t)E * 4);
  unsigned short* hbf = (unsigned short*)alloc((size_t)Mpad * DD * 2);
  unsigned short* xbf = (unsigned short*)alloc((size_t)Mpad * DD * 2);
  unsigned short* aggbf = (unsigned short*)alloc((size_t)Mpad * DD * 2);
  unsigned short* Ut = (unsigned short*)alloc((size_t)NG * KK * 2);
  float* bias = (float*)alloc((size_t)NG * 4);
  unsigned short* G = (unsigned short*)alloc((size_t)N * NG * 2);
  (void)ws_size;
  (void)n_in;
  (void)out_size;

  const int* esrc = edge;
  const int* edst = edge + E;

  k_zero2<<<(N + 255) / 256, 256, 0, stream>>>(counts, cursor, N);
  k_count<<<(E + 255) / 256, 256, 0, stream>>>(edst, counts, E);
  k_scan<<<1, 1024, 0, stream>>>(counts, row_start, N);
  k_scatter<<<(E + 255) / 256, 256, 0, stream>>>(esrc, edst, row_start, cursor, csr, E);
  k_convert<<<((Mpad * DD / 4) + 255) / 256, 256, 0, stream>>>(h, x, hbf, xbf, N * DD, Mpad * DD);
  k_agg<<<(Mpad + 3) / 4, 256, 0, stream>>>(h, row_start, csr, aggbf, N, Mpad);
  k_fusew<<<(NG * KK + 255) / 256, 256, 0, stream>>>(
      Wg0, Wg1, Wg2, Wg3, Wl0, Wl1, Wl2, Wl3, Wr0, Wr1, Wr2, Wr3,
      bg0, bg1, bg2, bg3, bl0, bl1, bl2, bl3, Ut, bias);
  dim3 ggrid(Mpad / 128, 4);
  k_gemm<<<ggrid, 256, 0, stream>>>(hbf, xbf, aggbf, Ut, bias, G, N);
  k_final<<<(N + 3) / 4, 256, 0, stream>>>(G, cellp, gamma, beta, (float*)d_out, N);
}

// Round 2
// 237.063 us; speedup vs baseline: 1.3083x; 1.3083x over previous
//
#include <hip/hip_runtime.h>

#define DD 128
#define KK 384
#define NG 512

typedef __attribute__((ext_vector_type(8))) short bf16x8;
typedef __attribute__((ext_vector_type(4))) float f32x4;

__device__ __forceinline__ float bf2f(unsigned short u) {
  return __uint_as_float(((unsigned int)u) << 16);
}
__device__ __forceinline__ unsigned short f2bf(float f) {
  unsigned int x = __float_as_uint(f);
  x += 0x7fffu + ((x >> 16) & 1u);
  return (unsigned short)(x >> 16);
}

__global__ void k_zero2(int* __restrict__ a, int* __restrict__ b,
                        int* __restrict__ gcur, int n) {
  int i = blockIdx.x * blockDim.x + threadIdx.x;
  if (i < n) { a[i] = 0; b[i] = 0; }
  if (i == 0) *gcur = 0;
}

__global__ void k_count(const int* __restrict__ dst, int* __restrict__ counts, int E) {
  int e = blockIdx.x * blockDim.x + threadIdx.x;
  if (e < E) atomicAdd(counts + dst[e], 1);
}

// Assign each node a contiguous CSR segment. Placement order across waves is
// atomic-order-dependent (harmless: only changes intra-sum order, like the
// scatter cursor already does); segment start = base + wave-exclusive-scan.
__global__ void k_partition(const int* __restrict__ counts, int* __restrict__ row_start,
                            int* __restrict__ gcur, int n) {
  int i = blockIdx.x * blockDim.x + threadIdx.x;
  int lane = threadIdx.x & 63;
  int v = (i < n) ? counts[i] : 0;
  int s = v;
#pragma unroll
  for (int off = 1; off < 64; off <<= 1) {
    int t = __shfl_up(s, off);
    if (lane >= off) s += t;
  }
  int total = __shfl(s, 63);
  int base = 0;
  if (lane == 63) base = atomicAdd(gcur, total);
  base = __shfl(base, 63);
  if (i < n) row_start[i] = base + s - v;
}

__global__ void k_scatter(const int* __restrict__ srcv, const int* __restrict__ dstv,
                          const int* __restrict__ row_start, int* __restrict__ cursor,
                          int* __restrict__ csr, int E) {
  int e = blockIdx.x * blockDim.x + threadIdx.x;
  if (e < E) {
    int d = dstv[e];
    int pos = row_start[d] + atomicAdd(cursor + d, 1);
    csr[pos] = srcv[e];
  }
}

__global__ void k_convert(const float* __restrict__ h, const float* __restrict__ x,
                          unsigned short* __restrict__ hbf, unsigned short* __restrict__ xbf,
                          int n128, int mpad128) {
  int i = (blockIdx.x * blockDim.x + threadIdx.x) * 4;
  if (i >= mpad128) return;
  ushort4 ho, xo;
  if (i < n128) {
    float4 hv = *(const float4*)(h + i);
    float4 xv = *(const float4*)(x + i);
    ho = make_ushort4(f2bf(hv.x), f2bf(hv.y), f2bf(hv.z), f2bf(hv.w));
    xo = make_ushort4(f2bf(xv.x), f2bf(xv.y), f2bf(xv.z), f2bf(xv.w));
  } else {
    ho = make_ushort4(0, 0, 0, 0);
    xo = make_ushort4(0, 0, 0, 0);
  }
  *(ushort4*)(hbf + i) = ho;
  *(ushort4*)(xbf + i) = xo;
}

// One wave per node. 4 neighbor-groups x 16 lanes x bf16x8(16B) per row.
__global__ void k_agg(const unsigned short* __restrict__ hbf, const int* __restrict__ row_start,
                      const int* __restrict__ counts, const int* __restrict__ csr,
                      unsigned short* __restrict__ aggbf, int n, int mpad) {
  int wave = (blockIdx.x * blockDim.x + threadIdx.x) >> 6;
  int lane = threadIdx.x & 63;
  if (wave >= mpad) return;
  int g = lane >> 4;
  int t = lane & 15;
  float acc[8] = {0.f, 0.f, 0.f, 0.f, 0.f, 0.f, 0.f, 0.f};
  if (wave < n) {
    int s = row_start[wave], deg = counts[wave];
    int e = s + deg;
    for (int j = s; j < e; j += 4) {
      int jj = j + g;
      if (jj < e) {
        int src = csr[jj];
        bf16x8 v = *(const bf16x8*)(hbf + (size_t)src * DD + t * 8);
#pragma unroll
        for (int q = 0; q < 8; ++q) acc[q] += bf2f((unsigned short)v[q]);
      }
    }
#pragma unroll
    for (int q = 0; q < 8; ++q) {
      acc[q] += __shfl_xor(acc[q], 16);
      acc[q] += __shfl_xor(acc[q], 32);
    }
    float inv = 1.f / fmaxf((float)deg, 1.f);
#pragma unroll
    for (int q = 0; q < 8; ++q) acc[q] *= inv;
  }
  if (g == 0) {
    bf16x8 o;
#pragma unroll
    for (int q = 0; q < 8; ++q) o[q] = (short)f2bf(acc[q]);
    *(bf16x8*)(aggbf + (size_t)wave * DD + t * 8) = o;
  }
}

__global__ void k_fusew(const float* __restrict__ Wg0, const float* __restrict__ Wg1,
                        const float* __restrict__ Wg2, const float* __restrict__ Wg3,
                        const float* __restrict__ Wl0, const float* __restrict__ Wl1,
                        const float* __restrict__ Wl2, const float* __restrict__ Wl3,
                        const float* __restrict__ Wr0, const float* __restrict__ Wr1,
                        const float* __restrict__ Wr2, const float* __restrict__ Wr3,
                        const float* __restrict__ bg0, const float* __restrict__ bg1,
                        const float* __restrict__ bg2, const float* __restrict__ bg3,
                        const float* __restrict__ bl0, const float* __restrict__ bl1,
                        const float* __restrict__ bl2, const float* __restrict__ bl3,
                        unsigned short* __restrict__ Ut, float* __restrict__ bias) {
  int id = blockIdx.x * blockDim.x + threadIdx.x;
  if (id >= NG * KK) return;
  int nn = id / KK, k = id % KK;
  int g = nn >> 7, c = nn & 127;
  const float* Wg = g == 0 ? Wg0 : g == 1 ? Wg1 : g == 2 ? Wg2 : Wg3;
  const float* Wl = g == 0 ? Wl0 : g == 1 ? Wl1 : g == 2 ? Wl2 : Wl3;
  const float* Wr = g == 0 ? Wr0 : g == 1 ? Wr1 : g == 2 ? Wr2 : Wr3;
  float v;
  if (k < 128)      v = Wg[k * DD + c] + Wr[k * DD + c];
  else if (k < 256) v = Wg[k * DD + c];
  else              v = Wl[(k - 256) * DD + c];
  Ut[(size_t)nn * KK + k] = f2bf(v);
  if (k == 0) {
    const float* bgp = g == 0 ? bg0 : g == 1 ? bg1 : g == 2 ? bg2 : bg3;
    const float* blp = g == 0 ? bl0 : g == 1 ? bl1 : g == 2 ? bl2 : bl3;
    bias[nn] = bgp[c] + blp[c];
  }
}

__device__ __forceinline__ void gload16(const void* g, void* l) {
  __builtin_amdgcn_global_load_lds((__attribute__((address_space(1))) void*)(void*)g,
                                   (__attribute__((address_space(3))) void*)l, 16, 0, 0);
}

__global__ __launch_bounds__(256) void k_gemm(
    const unsigned short* __restrict__ hbf, const unsigned short* __restrict__ xbf,
    const unsigned short* __restrict__ aggbf, const unsigned short* __restrict__ Ut,
    const float* __restrict__ bias, unsigned short* __restrict__ G, int nrows) {
  __shared__ unsigned short As[128 * 64];
  __shared__ unsigned short Bs[128 * 64];
  int m0 = blockIdx.x * 128;
  int n0 = blockIdx.y * 128;
  int tid = threadIdx.x;
  int w = tid >> 6, lane = tid & 63;
  int wr = w >> 1, wc = w & 1;
  f32x4 acc[4][4] = {};

  int srow[4], sslot[4];
#pragma unroll
  for (int p = 0; p < 4; ++p) {
    int off = w * 4096 + p * 1024 + lane * 16;
    srow[p] = off >> 7;
    sslot[p] = (lane & 7) ^ (srow[p] & 7);
  }

  for (int ks = 0; ks < 6; ++ks) {
    const unsigned short* Ab = ks < 2 ? hbf : (ks < 4 ? xbf : aggbf);
    int akoff = (ks & 1) * 128;
    int bkoff = ks * 128;
#pragma unroll
    for (int p = 0; p < 4; ++p) {
      const char* ga = (const char*)Ab + (size_t)(m0 + srow[p]) * 256 + akoff + sslot[p] * 16;
      gload16(ga, (char*)As + w * 4096 + p * 1024);
      const char* gb = (const char*)Ut + (size_t)(n0 + srow[p]) * 768 + bkoff + sslot[p] * 16;
      gload16(gb, (char*)Bs + w * 4096 + p * 1024);
    }
    asm volatile("s_waitcnt vmcnt(0)" ::: "memory");
    __syncthreads();

    bf16x8 af[4][2], bfr[4][2];
    int rg = lane >> 4;
#pragma unroll
    for (int mi = 0; mi < 4; ++mi) {
      int r = wr * 64 + mi * 16 + (lane & 15);
#pragma unroll
      for (int k2 = 0; k2 < 2; ++k2) {
        int s = (k2 * 4 + rg) ^ (r & 7);
        af[mi][k2] = *(const bf16x8*)((const char*)As + r * 128 + s * 16);
      }
    }
#pragma unroll
    for (int ni = 0; ni < 4; ++ni) {
      int r = wc * 64 + ni * 16 + (lane & 15);
#pragma unroll
      for (int k2 = 0; k2 < 2; ++k2) {
        int s = (k2 * 4 + rg) ^ (r & 7);
        bfr[ni][k2] = *(const bf16x8*)((const char*)Bs + r * 128 + s * 16);
      }
    }
#pragma unroll
    for (int mi = 0; mi < 4; ++mi)
#pragma unroll
      for (int ni = 0; ni < 4; ++ni) {
        acc[mi][ni] = __builtin_amdgcn_mfma_f32_16x16x32_bf16(af[mi][0], bfr[ni][0], acc[mi][ni], 0, 0, 0);
        acc[mi][ni] = __builtin_amdgcn_mfma_f32_16x16x32_bf16(af[mi][1], bfr[ni][1], acc[mi][ni], 0, 0, 0);
      }
    __syncthreads();
  }

  int colb = n0 + wc * 64;
#pragma unroll
  for (int ni = 0; ni < 4; ++ni) {
    int col = colb + ni * 16 + (lane & 15);
    float bi = bias[col];
#pragma unroll
    for (int mi = 0; mi < 4; ++mi) {
      int rowb = m0 + wr * 64 + mi * 16 + (lane >> 4) * 4;
#pragma unroll
      for (int j = 0; j < 4; ++j) {
        int row = rowb + j;
        if (row < nrows) G[(size_t)row * NG + col] = f2bf(acc[mi][ni][j] + bi);
      }
    }
  }
}

__global__ void k_final(const unsigned short* __restrict__ G, const float* __restrict__ cell,
                        const float* __restrict__ gamma, const float* __restrict__ beta,
                        float* __restrict__ out, int n) {
  int wave = (blockIdx.x * blockDim.x + threadIdx.x) >> 6;
  int lane = threadIdx.x & 63;
  if (wave >= n) return;
  const unsigned short* g = G + (size_t)wave * NG;
  int c = lane * 2;
  ushort2 fu = *(const ushort2*)(g + c);
  ushort2 iu = *(const ushort2*)(g + 128 + c);
  ushort2 cu = *(const ushort2*)(g + 256 + c);
  ushort2 ou = *(const ushort2*)(g + 384 + c);
  float2 cv = *(const float2*)(cell + (size_t)wave * DD + c);
  float f0 = 1.f / (1.f + expf(-bf2f(fu.x)));
  float f1 = 1.f / (1.f + expf(-bf2f(fu.y)));
  float i0 = 1.f / (1.f + expf(-bf2f(iu.x)));
  float i1 = 1.f / (1.f + expf(-bf2f(iu.y)));
  float t0 = tanhf(bf2f(cu.x));
  float t1 = tanhf(bf2f(cu.y));
  float o0 = 1.f / (1.f + expf(-bf2f(ou.x)));
  float o1 = 1.f / (1.f + expf(-bf2f(ou.y)));
  float cn0 = f0 * cv.x + i0 * t0;
  float cn1 = f1 * cv.y + i1 * t1;
  float y0 = o0 * tanhf(cn0);
  float y1 = o1 * tanhf(cn1);
  float s = y0 + y1, s2 = y0 * y0 + y1 * y1;
#pragma unroll
  for (int off = 1; off < 64; off <<= 1) {
    s += __shfl_xor(s, off);
    s2 += __shfl_xor(s2, off);
  }
  float mean = s * (1.f / 128.f);
  float var = s2 * (1.f / 128.f) - mean * mean;
  float rstd = rsqrtf(var + 1e-5f);
  float2 gm = *(const float2*)(gamma + c);
  float2 bt = *(const float2*)(beta + c);
  float h0 = (y0 - mean) * rstd * gm.x + bt.x;
  float h1 = (y1 - mean) * rstd * gm.y + bt.y;
  *(float2*)(out + (size_t)wave * DD + c) = make_float2(h0, h1);
  *(float2*)(out + (size_t)n * DD + (size_t)wave * DD + c) = make_float2(cn0, cn1);
}

extern "C" void kernel_launch(void* const* d_in, const int* in_sizes, int n_in,
                              void* d_out, int out_size, void* d_ws, size_t ws_size,
                              hipStream_t stream) {
  const float* h = (const float*)d_in[0];
  const float* cellp = (const float*)d_in[1];
  const float* x = (const float*)d_in[2];
  const int* edge = (const int*)d_in[3];
  const float* Wg0 = (const float*)d_in[4];
  const float* bg0 = (const float*)d_in[5];
  const float* Wg1 = (const float*)d_in[6];
  const float* bg1 = (const float*)d_in[7];
  const float* Wg2 = (const float*)d_in[8];
  const float* bg2 = (const float*)d_in[9];
  const float* Wg3 = (const float*)d_in[10];
  const float* bg3 = (const float*)d_in[11];
  const float* Wl0 = (const float*)d_in[12];
  const float* bl0 = (const float*)d_in[13];
  const float* Wr0 = (const float*)d_in[14];
  const float* Wl1 = (const float*)d_in[15];
  const float* bl1 = (const float*)d_in[16];
  const float* Wr1 = (const float*)d_in[17];
  const float* Wl2 = (const float*)d_in[18];
  const float* bl2 = (const float*)d_in[19];
  const float* Wr2 = (const float*)d_in[20];
  const float* Wl3 = (const float*)d_in[21];
  const float* bl3 = (const float*)d_in[22];
  const float* Wr3 = (const float*)d_in[23];
  const float* gamma = (const float*)d_in[24];
  const float* beta = (const float*)d_in[25];

  int N = in_sizes[0] / DD;
  int E = in_sizes[3] / 2;
  int Mpad = ((N + 127) / 128) * 128;

  char* ws = (char*)d_ws;
  size_t off = 0;
  auto alloc = [&](size_t b) {
    char* p = ws + off;
    off += (b + 255) & ~(size_t)255;
    return p;
  };
  int* counts = (int*)alloc((size_t)N * 4);
  int* cursor = (int*)alloc((size_t)N * 4);
  int* row_start = (int*)alloc((size_t)N * 4);
  int* gcur = (int*)alloc(4);
  int* csr = (int*)alloc((size_t)E * 4);
  unsigned short* hbf = (unsigned short*)alloc((size_t)Mpad * DD * 2);
  unsigned short* xbf = (unsigned short*)alloc((size_t)Mpad * DD * 2);
  unsigned short* aggbf = (unsigned short*)alloc((size_t)Mpad * DD * 2);
  unsigned short* Ut = (unsigned short*)alloc((size_t)NG * KK * 2);
  float* bias = (float*)alloc((size_t)NG * 4);
  unsigned short* G = (unsigned short*)alloc((size_t)N * NG * 2);
  (void)ws_size;
  (void)n_in;
  (void)out_size;

  const int* esrc = edge;
  const int* edst = edge + E;

  k_zero2<<<(N + 255) / 256, 256, 0, stream>>>(counts, cursor, gcur, N);
  k_count<<<(E + 255) / 256, 256, 0, stream>>>(edst, counts, E);
  k_partition<<<(N + 255) / 256, 256, 0, stream>>>(counts, row_start, gcur, N);
  k_scatter<<<(E + 255) / 256, 256, 0, stream>>>(esrc, edst, row_start, cursor, csr, E);
  k_convert<<<((Mpad * DD / 4) + 255) / 256, 256, 0, stream>>>(h, x, hbf, xbf, N * DD, Mpad * DD);
  k_agg<<<(Mpad + 3) / 4, 256, 0, stream>>>(hbf, row_start, counts, csr, aggbf, N, Mpad);
  k_fusew<<<(NG * KK + 255) / 256, 256, 0, stream>>>(
      Wg0, Wg1, Wg2, Wg3, Wl0, Wl1, Wl2, Wl3, Wr0, Wr1, Wr2, Wr3,
      bg0, bg1, bg2, bg3, bl0, bl1, bl2, bl3, Ut, bias);
  dim3 ggrid(Mpad / 128, 4);
  k_gemm<<<ggrid, 256, 0, stream>>>(hbf, xbf, aggbf, Ut, bias, G, N);
  k_final<<<(N + 3) / 4, 256, 0, stream>>>(G, cellp, gamma, beta, (float*)d_out, N);
}